// Round 8
// baseline (164.733 us; speedup 1.0000x reference)
//
#include <hip/hip_runtime.h>
#include <math.h>

// Problem constants
#define VDIM   128
#define KCODES 512
#define NROWS  (32 * 4096)       // 131072
#define TILE_ROWS 256            // rows per block (16 waves x 16 rows)
#define NBLK (NROWS / TILE_ROWS) // 512 blocks = 2 per CU
#define STAGE_CODES 256          // codes per LDS stage (64 KB)
#define TN 0.67882250993908565f  // 0.06 * sqrt(128)

typedef __attribute__((ext_vector_type(8))) short bf16x8;  // MFMA A/B frag (4 VGPR)
typedef __attribute__((ext_vector_type(4))) float f32x4;   // MFMA C/D frag / 16B ld-st

__device__ __forceinline__ unsigned short f2bf(float f) {
    unsigned u = __float_as_uint(f);
    unsigned r = u + 0x7FFFu + ((u >> 16) & 1u);   // round-to-nearest-even
    return (unsigned short)(r >> 16);
}

__device__ __forceinline__ bf16x8 pack8(f32x4 a, f32x4 b) {
    bf16x8 v;
    v[0] = (short)f2bf(a[0]); v[1] = (short)f2bf(a[1]);
    v[2] = (short)f2bf(a[2]); v[3] = (short)f2bf(a[3]);
    v[4] = (short)f2bf(b[0]); v[5] = (short)f2bf(b[1]);
    v[6] = (short)f2bf(b[2]); v[7] = (short)f2bf(b[3]);
    return v;
}

// OCCUPANCY build: 16 waves x 16 rows, 2 blocks per CU (the first variant to
// exceed the 50% wave cap). Evidence: occupancy tracked duration monotonically
// across r0-r7 (22%->100us, 27-33%->75-88us, 42%->66us) while every pipe sat
// <40% busy. LDS halved to ~71 KB via 2-stage half-table staging; VGPR capped
// at 64 by __launch_bounds__(1024,8) -- the compiler naturally allocates 64
// here (it has sunk the x0 loads every round regardless of pinning), which is
// exactly the 8-waves/SIMD budget. Latency now hidden by TLP, not prefetch.
// Kept from prior rounds: fragment-linear conflict-free LDS layout, owner-lane
// shfl-free epilogue (r6: bank conflicts 137k->11k), LDS histogram with one
// per-block flush, argmin==argmax(dot) identity.
__global__ __launch_bounds__(1024, 8) void vq_fused(
        const float* __restrict__ x0,
        const float* __restrict__ emb0,
        unsigned* __restrict__ hist,
        float* __restrict__ out0,
        float* __restrict__ out1,
        float* __restrict__ out2) {
    __shared__ uint4 sB[4096];              // 64 KB: half-table, fragment-linear
    __shared__ float sscale[KCODES];        // TN / ||emb0_k||
    __shared__ int   shist[KCODES];         // per-block histogram
    __shared__ int   sbesti[TILE_ROWS];     // per-row winning code

    int t = threadIdx.x;
    int w = t >> 6;           // wave 0..15
    int l = t & 63;
    int n15 = l & 15;         // MFMA m (A rows), n (B cols), col (C)
    int q = l >> 4;           // quad: input k = q*8 + j; C row = q*4 + r

    int rowbase = blockIdx.x * TILE_ROWS + (w << 4);   // 16 rows per wave

    // ---- x0 loads (compiler will schedule; TLP hides the latency)
    f32x4 ax[4][2];
    {
        const float* xrow = x0 + (size_t)(rowbase + n15) * VDIM + (q << 3);
        #pragma unroll
        for (int kc = 0; kc < 4; ++kc) {
            const f32x4* xp = (const f32x4*)(xrow + (kc << 5));
            ax[kc][0] = xp[0];
            ax[kc][1] = xp[1];
        }
    }

    if (t < KCODES) shist[t] = 0;

    // ---- Norm phase: wave w computes codes w*32 .. w*32+31.
    #pragma unroll 4
    for (int i = 0; i < 32; ++i) {
        int k = (w << 5) + i;
        const float* row = emb0 + (size_t)k * VDIM;
        float a = row[l];
        float b = row[l + 64];
        float ss = a * a + b * b;
        #pragma unroll
        for (int off = 32; off; off >>= 1) ss += __shfl_xor(ss, off);
        if (l == 0) sscale[k] = TN / sqrtf(ss);
    }

    __syncthreads();        // sscale + shist-zero visible

    // ---- Pack A fragments + row norms
    bf16x8 afr[4];
    float nsq;
    {
        float p0 = 0.f, p1 = 0.f;
        #pragma unroll
        for (int kc = 0; kc < 4; ++kc) {
            f32x4 a = ax[kc][0], b = ax[kc][1];
            p0 = fmaf(a[0], a[0], p0); p1 = fmaf(a[1], a[1], p1);
            p0 = fmaf(a[2], a[2], p0); p1 = fmaf(a[3], a[3], p1);
            p0 = fmaf(b[0], b[0], p0); p1 = fmaf(b[1], b[1], p1);
            p0 = fmaf(b[2], b[2], p0); p1 = fmaf(b[3], b[3], p1);
            afr[kc] = pack8(a, b);
        }
        nsq = p0 + p1;
        nsq += __shfl_xor(nsq, 16, 64);   // full ||x0_row||^2 across quads
        nsq += __shfl_xor(nsq, 32, 64);
    }

    float best[4];
    int   bidx[4];
    #pragma unroll
    for (int r = 0; r < 4; ++r) { best[r] = -3.4e38f; bidx[r] = 0; }

    const f32x4 zero4 = {0.f, 0.f, 0.f, 0.f};

    // ---- 2 stages of 256 codes each
    #pragma unroll 1
    for (int st = 0; st < 2; ++st) {
        if (st) __syncthreads();    // stage-0 table fully consumed

        // Build half-table: granule g holds dims [d0,d0+8) of local code kl,
        //   kl = (g>>8)*16 + (g&15),  d0 = ((g>>4)&15)*8.  4 granules/thread.
        int kofs = st << 8;
        #pragma unroll
        for (int i = 0; i < 4; ++i) {
            int g = (i << 10) + t;
            int k = kofs + (((g >> 8) << 4) | (g & 15));
            int d0 = ((g >> 4) & 15) << 3;
            float s = sscale[k];
            const f32x4* ep = (const f32x4*)(emb0 + (size_t)k * VDIM + d0);
            f32x4 a = ep[0], b = ep[1];
            f32x4 as, bs;
            as[0] = a[0] * s; as[1] = a[1] * s; as[2] = a[2] * s; as[3] = a[3] * s;
            bs[0] = b[0] * s; bs[1] = b[1] * s; bs[2] = b[2] * s; bs[3] = b[3] * s;
            ((bf16x8*)sB)[g] = pack8(as, bs);
        }
        __syncthreads();

        // 16 chunks of 16 codes, B frags from LDS (stride-1, conflict-free)
        #pragma unroll 2
        for (int cn = 0; cn < 16; ++cn) {
            const bf16x8* bls = ((const bf16x8*)sB) + (cn << 8) + l;
            bf16x8 b0 = bls[0], b1 = bls[64], b2 = bls[128], b3 = bls[192];
            int nbase = kofs + (cn << 4) + n15;
            f32x4 acc = __builtin_amdgcn_mfma_f32_16x16x32_bf16(afr[0], b0, zero4, 0, 0, 0);
            acc = __builtin_amdgcn_mfma_f32_16x16x32_bf16(afr[1], b1, acc, 0, 0, 0);
            acc = __builtin_amdgcn_mfma_f32_16x16x32_bf16(afr[2], b2, acc, 0, 0, 0);
            acc = __builtin_amdgcn_mfma_f32_16x16x32_bf16(afr[3], b3, acc, 0, 0, 0);
            #pragma unroll
            for (int r = 0; r < 4; ++r) {
                float d = acc[r];
                if (d > best[r]) { best[r] = d; bidx[r] = nbase; }
            }
        }
    }

    // ---- Reduce argmax across the 16 lanes (C cols) holding the same row
    #pragma unroll
    for (int m = 1; m <= 8; m <<= 1) {
        #pragma unroll
        for (int r = 0; r < 4; ++r) {
            float ov = __shfl_xor(best[r], m, 64);
            int   oi = __shfl_xor(bidx[r], m, 64);
            if (ov > best[r] || (ov == best[r] && oi < bidx[r])) {
                best[r] = ov; bidx[r] = oi;
            }
        }
    }

    // ---- Owner-lane epilogue (no shfl): lane l = (rl>>2)*16 + rl owns row
    // rl = l&15 (requires (l&15)>>2 == q); result in slot [l&3], norm = nsq.
    int r3 = l & 3;
    bool own = (((l & 15) >> 2) == q);
    if (own) {
        int rl = l & 15;
        size_t row = (size_t)rowbase + rl;
        float dv = best[r3];
        int   bv = bidx[r3];
        float sc = TN / sqrtf(nsq);                  // x = sc * x0
        float o1 = 2.f * TN * TN - 2.f * sc * dv;    // ||x||=||e||=tn
        __builtin_nontemporal_store(o1, &out1[row]);
        float sm = sc - 1.f;
        __builtin_nontemporal_store(o1 + sm * sm * nsq, &out2[row]);
        atomicAdd(&shist[bv], 1);
        sbesti[(w << 4) + rl] = bv;
    }

    // ---- Wave-local out0: 8 passes x 2 rows (64 lanes x 16B contiguous).
    // bi via LDS broadcast of this wave's own sbesti entries (same-wave RAW).
    #pragma unroll 4
    for (int p = 0; p < 8; ++p) {
        int rl = (p << 1) + (l >> 5);
        int bi = sbesti[(w << 4) + rl];
        float s = sscale[bi];
        int v4 = l & 31;
        f32x4 e = *((const f32x4*)(emb0 + (size_t)bi * VDIM) + v4);
        f32x4 o;
        o[0] = e[0] * s; o[1] = e[1] * s; o[2] = e[2] * s; o[3] = e[3] * s;
        __builtin_nontemporal_store(
            o, (f32x4*)(out0 + ((size_t)rowbase + rl) * (size_t)VDIM) + v4);
    }

    __syncthreads();        // all waves' histogram contributions landed

    // ---- One global-atomic flush per (block, nonzero code)
    if (t < KCODES && shist[t]) atomicAdd(&hist[t], (unsigned)shist[t]);
}

__global__ void entropy_k(const unsigned* __restrict__ hist,
                          float* __restrict__ out) {
    __shared__ float red[8];
    int t = threadIdx.x;   // KCODES threads
    float h = (float)hist[t];
    float p = h / (float)NROWS;
    float term = (h > 0.f) ? p * logf(p) : 0.f;
    #pragma unroll
    for (int off = 32; off; off >>= 1) term += __shfl_xor(term, off);
    if ((t & 63) == 0) red[t >> 6] = term;
    __syncthreads();
    if (t == 0) {
        float ssum = 0.f;
        #pragma unroll
        for (int i = 0; i < 8; i++) ssum += red[i];
        out[0] = -ssum;
    }
}

extern "C" void kernel_launch(void* const* d_in, const int* in_sizes, int n_in,
                              void* d_out, int out_size, void* d_ws, size_t ws_size,
                              hipStream_t stream) {
    const float* x0   = (const float*)d_in[0];
    const float* emb0 = (const float*)d_in[1];

    unsigned* hist = (unsigned*)d_ws;                    // 512 u32 = 2 KB

    float* out  = (float*)d_out;
    float* out0 = out;
    float* out1 = out0 + (size_t)NROWS * VDIM;
    float* out2 = out1 + NROWS;
    float* oent = out2 + NROWS;

    hipMemsetAsync(hist, 0, KCODES * sizeof(unsigned), stream);
    vq_fused<<<NBLK, 1024, 0, stream>>>(x0, emb0, hist, out0, out1, out2);
    entropy_k<<<1, KCODES, 0, stream>>>(hist, oent);
}